// Round 13
// baseline (353.136 us; speedup 1.0000x reference)
//
#include <hip/hip_runtime.h>
#include <hip/hip_bf16.h>

#define DEV __device__ __forceinline__

typedef float f32x4 __attribute__((ext_vector_type(4)));
typedef short short8 __attribute__((ext_vector_type(8)));
typedef short short4v __attribute__((ext_vector_type(4)));

#if __has_builtin(__builtin_amdgcn_exp2f)
#define EXP2F __builtin_amdgcn_exp2f
#else
#define EXP2F exp2f
#endif
#if __has_builtin(__builtin_amdgcn_rcpf)
#define RCPF __builtin_amdgcn_rcpf
#else
#define RCPF(x) (1.f / (x))
#endif

DEV short f2bf(float f) {
    union { float f; unsigned u; } c; c.f = f;
    unsigned r = (c.u + 0x7FFFu + ((c.u >> 16) & 1u)) >> 16;  // RNE
    return (short)r;
}

DEV int cvt_pk_bf16(float lo, float hi) {
    int d;
    asm("v_cvt_pk_bf16_f32 %0, %1, %2" : "=v"(d) : "v"(lo), "v"(hi));
    return d;
}

// lean tanh-approx gelu: HW exp2/rcp only. max |err| vs erf-gelu ~2e-4.
DEV float gelu_fast(float x) {
    float x2 = x * x;
    float y = x * __builtin_fmaf(0.0356774081f, x2, 0.7978845608f);
    y = fminf(fmaxf(y, -15.f), 15.f);
    float e = EXP2F(y * 2.8853900817779268f);     // e^(2y)
    float r = RCPF(e + 1.f);
    float t = (e - 1.f) * r;                      // tanh(y)
    return 0.5f * x * (1.f + t);
}

// sigmoid-form gelu: x*sigmoid(1.702x), 5 VALU. disto A-operand only.
DEV float gelu_sig(float x) {
    float e = EXP2F(x * -2.4555282f);   // exp(-1.702x)
    return x * RCPF(1.f + e);
}

DEV float wred_sum(float v) {
    #pragma unroll
    for (int off = 1; off < 64; off <<= 1) v += __shfl_xor(v, off);
    return v;
}

// ---------------- fused weight-cvt (blocks 512..1023) + embed (0..511) --------
struct CvtPack {
    const float* s[9];
    short* d[9];
    int n[9];
};
__global__ __launch_bounds__(256) void k_cvt_embed(CvtPack p,
                                                   const int* __restrict__ tokens,
                                                   const float* __restrict__ emb,
                                                   float* __restrict__ x,
                                                   short* __restrict__ xb) {
    if (blockIdx.x < 512) {
        int n = blockIdx.x, d = threadIdx.x;
        int tok = tokens[n];
        float div = expf((float)((d >> 1) * 2) * -0.035977892079030837f); // -ln(1e4)/256
        float arg = (float)n * div;
        float pe = (d & 1) ? cosf(arg) : sinf(arg);
        float v = emb[tok * 256 + d] + pe;
        x[n * 256 + d] = v;
        xb[n * 256 + d] = f2bf(v);
        return;
    }
    int bid = blockIdx.x - 512;
    #pragma unroll 1
    for (int seg = 0; seg < 9; ++seg) {
        int n4 = p.n[seg] >> 2;
        const float4* src = (const float4*)p.s[seg];
        short4v* dst = (short4v*)p.d[seg];
        for (int i = bid * 256 + threadIdx.x; i < n4; i += 512 * 256) {
            float4 v = src[i];
            short4v o;
            o[0] = f2bf(v.x); o[1] = f2bf(v.y); o[2] = f2bf(v.z); o[3] = f2bf(v.w);
            dst[i] = o;
        }
    }
}

// ---------------- bf16 MFMA GEMM, 16x16 tile per wave (r11-verified) ----------
__global__ __launch_bounds__(64) void k_gemm16(const short* __restrict__ A,
                                               const short* __restrict__ W,
                                               const float* __restrict__ bias,
                                               float* __restrict__ outf,
                                               short* __restrict__ outb,
                                               short* __restrict__ vt,
                                               int M, int K, int ldw, int act) {
    int m0 = blockIdx.x * 16, n0 = blockIdx.y * 16;
    int lane = threadIdx.x;
    int cr = lane & 15, g = lane >> 4;
    const short* a0 = A + (size_t)(n0 + cr) * K + g * 8;
    const short* b0 = W + (size_t)(m0 + cr) * ldw + g * 8;
    f32x4 acc = {0.f, 0.f, 0.f, 0.f};
    #pragma unroll 1
    for (int kc = 0; kc < K; kc += 256) {
        short8 af[8], bf8[8];
        #pragma unroll
        for (int ki = 0; ki < 8; ++ki) af[ki] = *(const short8*)(a0 + kc + ki * 32);
        #pragma unroll
        for (int ki = 0; ki < 8; ++ki) bf8[ki] = *(const short8*)(b0 + kc + ki * 32);
        #pragma unroll
        for (int ki = 0; ki < 8; ++ki)
            acc = __builtin_amdgcn_mfma_f32_16x16x32_bf16(af[ki], bf8[ki], acc, 0, 0, 0);
    }
    float bb = bias ? bias[m0 + cr] : 0.f;
    int m = m0 + cr;
    #pragma unroll
    for (int r = 0; r < 4; ++r) {
        int row = n0 + g * 4 + r;
        float v = acc[r] + bb;
        if (act == 1) v = fmaxf(v, 0.f);
        else if (act == 2) v = gelu_fast(v);
        else if (act == 3) v = 1.f / (1.f + __expf(-v));
        if (outf) outf[(size_t)row * M + m] = v;
        if (outb) outb[(size_t)row * M + m] = f2bf(v);
        if (vt && m >= 512) vt[(size_t)(m - 512) * 512 + row] = f2bf(v);
    }
}

// ---------------- F1 merged GEMM: hij[n][0:256]=lat@F1L^T+f1b, [256:512]=lat@F1R^T
__global__ __launch_bounds__(64) void k_gemm_f1(const short* __restrict__ A,
                                                const short* __restrict__ F1,
                                                const float* __restrict__ f1b,
                                                float* __restrict__ hij) {
    int m0 = blockIdx.x * 16, n0 = blockIdx.y * 16;
    int lane = threadIdx.x;
    int cr = lane & 15, g = lane >> 4;
    const short* a0 = A + (size_t)(n0 + cr) * 256 + g * 8;
    const short* b0 = (m0 < 256)
        ? F1 + (size_t)(m0 + cr) * 512 + g * 8
        : F1 + (size_t)(m0 - 256 + cr) * 512 + 256 + g * 8;
    f32x4 acc = {0.f, 0.f, 0.f, 0.f};
    short8 af[8], bf8[8];
    #pragma unroll
    for (int ki = 0; ki < 8; ++ki) af[ki] = *(const short8*)(a0 + ki * 32);
    #pragma unroll
    for (int ki = 0; ki < 8; ++ki) bf8[ki] = *(const short8*)(b0 + ki * 32);
    #pragma unroll
    for (int ki = 0; ki < 8; ++ki)
        acc = __builtin_amdgcn_mfma_f32_16x16x32_bf16(af[ki], bf8[ki], acc, 0, 0, 0);
    float bb = (m0 < 256) ? f1b[m0 + cr] : 0.f;
    int m = m0 + cr;
    #pragma unroll
    for (int r = 0; r < 4; ++r) {
        int row = n0 + g * 4 + r;
        hij[(size_t)row * 512 + m] = acc[r] + bb;
    }
}

// ---------------- MFMA flash attention v3 (verified r8) ----------------
__global__ __launch_bounds__(64) void k_attn3(const short* __restrict__ qkvb,
                                              const short* __restrict__ vt,
                                              short* __restrict__ obuf_bf) {
    __shared__ __align__(16) short Pb[16][40];
    int h = blockIdx.x, qt = blockIdx.y;
    int lane = threadIdx.x;
    int cr = lane & 15, g = lane >> 4;
    int qb = qt * 16;
    short8 qf = *(const short8*)(qkvb + (size_t)(qb + cr) * 768 + h * 32 + g * 8);
    f32x4 s[32];
    #pragma unroll
    for (int jt = 0; jt < 32; ++jt) {
        short8 kf = *(const short8*)(qkvb + (size_t)(jt * 16 + cr) * 768 + 256 + h * 32 + g * 8);
        f32x4 z = {0.f, 0.f, 0.f, 0.f};
        s[jt] = __builtin_amdgcn_mfma_f32_16x16x32_bf16(qf, kf, z, 0, 0, 0);
    }
    const float sc = 0.17677669529663687f; // 1/sqrt(32)
    float m[4], l[4];
    #pragma unroll
    for (int r = 0; r < 4; ++r) {
        float mm = -1e30f;
        #pragma unroll
        for (int jt = 0; jt < 32; ++jt) mm = fmaxf(mm, s[jt][r]);
        #pragma unroll
        for (int off = 1; off < 16; off <<= 1) mm = fmaxf(mm, __shfl_xor(mm, off));
        m[r] = mm * sc;
    }
    #pragma unroll
    for (int r = 0; r < 4; ++r) {
        float ll = 0.f;
        #pragma unroll
        for (int jt = 0; jt < 32; ++jt) {
            float p = __expf(s[jt][r] * sc - m[r]);
            s[jt][r] = p;
            ll += p;
        }
        #pragma unroll
        for (int off = 1; off < 16; off <<= 1) ll += __shfl_xor(ll, off);
        l[r] = ll;
    }
    const short* vth0 = vt + (size_t)(h * 32 + cr) * 512;
    const short* vth1 = vt + (size_t)(h * 32 + 16 + cr) * 512;
    f32x4 o0 = {0.f,0.f,0.f,0.f}, o1 = o0;
    #pragma unroll
    for (int c = 0; c < 16; ++c) {
        #pragma unroll
        for (int r = 0; r < 4; ++r) {
            Pb[4 * g + r][cr]      = f2bf(s[2 * c][r]);
            Pb[4 * g + r][16 + cr] = f2bf(s[2 * c + 1][r]);
        }
        short8 pa = *(const short8*)&Pb[cr][g * 8];
        short8 v0 = *(const short8*)(vth0 + c * 32 + g * 8);
        short8 v1 = *(const short8*)(vth1 + c * 32 + g * 8);
        o0 = __builtin_amdgcn_mfma_f32_16x16x32_bf16(pa, v0, o0, 0, 0, 0);
        o1 = __builtin_amdgcn_mfma_f32_16x16x32_bf16(pa, v1, o1, 0, 0, 0);
    }
    #pragma unroll
    for (int r = 0; r < 4; ++r) {
        float inv = 1.f / l[r];
        int q = qb + 4 * g + r;
        short* op = obuf_bf + (size_t)q * 256 + h * 32;
        op[cr]      = f2bf(o0[r] * inv);
        op[16 + cr] = f2bf(o1[r] * inv);
    }
}

// ---------------- residual + LayerNorm (fp32 + bf16 out) ----------------
__global__ __launch_bounds__(64) void k_ln(const float* xr, const float* y,
                                           const float* __restrict__ g,
                                           const float* __restrict__ b,
                                           float* out, short* outb) {
    int n = blockIdx.x, lane = threadIdx.x;
    float4 xv = *(const float4*)(xr + (size_t)n * 256 + lane * 4);
    float4 yv = *(const float4*)(y + (size_t)n * 256 + lane * 4);
    float t0 = xv.x + yv.x, t1 = xv.y + yv.y, t2 = xv.z + yv.z, t3 = xv.w + yv.w;
    float s = t0 + t1 + t2 + t3;
    float sq = t0 * t0 + t1 * t1 + t2 * t2 + t3 * t3;
    s = wred_sum(s);
    sq = wred_sum(sq);
    float mean = s * (1.f / 256.f);
    float var = sq * (1.f / 256.f) - mean * mean;
    float rstd = rsqrtf(var + 1e-5f);
    float4 gv = *(const float4*)(g + lane * 4);
    float4 bv = *(const float4*)(b + lane * 4);
    float r0 = (t0 - mean) * rstd * gv.x + bv.x;
    float r1 = (t1 - mean) * rstd * gv.y + bv.y;
    float r2 = (t2 - mean) * rstd * gv.z + bv.z;
    float r3 = (t3 - mean) * rstd * gv.w + bv.w;
    *(float4*)(out + (size_t)n * 256 + lane * 4) = make_float4(r0, r1, r2, r3);
    short4v ob; ob[0] = f2bf(r0); ob[1] = f2bf(r1); ob[2] = f2bf(r2); ob[3] = f2bf(r3);
    *(short4v*)(outb + (size_t)n * 256 + lane * 4) = ob;
}

// ---------------- fused alpha head: gelu(A1 x) strip in LDS, dot with A2 -------
// grid 32 (16-row strips), 1024 thr (16 waves, wave w = m-tile w).
__global__ __launch_bounds__(1024) void k_alpha2(const short* __restrict__ x_bf,
                                                 const short* __restrict__ A1_bf,
                                                 const float* __restrict__ a1b,
                                                 const float* __restrict__ A2,
                                                 const float* __restrict__ a2b,
                                                 float* __restrict__ alpha) {
    __shared__ float strip[16][260];
    int n0 = blockIdx.x * 16;
    int t = threadIdx.x, w = t >> 6, lane = t & 63;
    int cr = lane & 15, g = lane >> 4;
    int m0 = w * 16;
    const short* a0 = x_bf + (size_t)(n0 + cr) * 256 + g * 8;
    const short* b0 = A1_bf + (size_t)(m0 + cr) * 256 + g * 8;
    f32x4 acc = {0.f, 0.f, 0.f, 0.f};
    short8 af[8], bf8[8];
    #pragma unroll
    for (int ki = 0; ki < 8; ++ki) af[ki] = *(const short8*)(a0 + ki * 32);
    #pragma unroll
    for (int ki = 0; ki < 8; ++ki) bf8[ki] = *(const short8*)(b0 + ki * 32);
    #pragma unroll
    for (int ki = 0; ki < 8; ++ki)
        acc = __builtin_amdgcn_mfma_f32_16x16x32_bf16(af[ki], bf8[ki], acc, 0, 0, 0);
    float bb = a1b[m0 + cr];
    #pragma unroll
    for (int r = 0; r < 4; ++r)
        strip[g * 4 + r][m0 + cr] = gelu_fast(acc[r] + bb);
    __syncthreads();
    // wave w reduces row w
    float4 sv = *(const float4*)&strip[w][lane * 4];
    float4 av = *(const float4*)(A2 + lane * 4);
    float s = sv.x * av.x + sv.y * av.y + sv.z * av.z + sv.w * av.w;
    s = wred_sum(s);
    if (lane == 0) {
        float ah = s + a2b[0];
        alpha[n0 + w] = 1.2f + 2.3f / (1.f + __expf(-ah));
    }
}

// ---------------- fused torsion head: gelu(T1 x) strip, dots with T2 -----------
__global__ __launch_bounds__(1024) void k_tors2(const short* __restrict__ lat_bf,
                                                const short* __restrict__ T1_bf,
                                                const float* __restrict__ t1b,
                                                const float* __restrict__ T2,
                                                const float* __restrict__ t2b,
                                                float* __restrict__ phi,
                                                float* __restrict__ psi) {
    __shared__ float strip[16][260];
    int n0 = blockIdx.x * 16;
    int t = threadIdx.x, w = t >> 6, lane = t & 63;
    int cr = lane & 15, g = lane >> 4;
    int m0 = w * 16;
    const short* a0 = lat_bf + (size_t)(n0 + cr) * 256 + g * 8;
    const short* b0 = T1_bf + (size_t)(m0 + cr) * 256 + g * 8;
    f32x4 acc = {0.f, 0.f, 0.f, 0.f};
    short8 af[8], bf8[8];
    #pragma unroll
    for (int ki = 0; ki < 8; ++ki) af[ki] = *(const short8*)(a0 + ki * 32);
    #pragma unroll
    for (int ki = 0; ki < 8; ++ki) bf8[ki] = *(const short8*)(b0 + ki * 32);
    #pragma unroll
    for (int ki = 0; ki < 8; ++ki)
        acc = __builtin_amdgcn_mfma_f32_16x16x32_bf16(af[ki], bf8[ki], acc, 0, 0, 0);
    float bb = t1b[m0 + cr];
    #pragma unroll
    for (int r = 0; r < 4; ++r)
        strip[g * 4 + r][m0 + cr] = gelu_fast(acc[r] + bb);
    __syncthreads();
    float4 sv = *(const float4*)&strip[w][lane * 4];
    float4 w0 = *(const float4*)(T2 + lane * 4);
    float4 w1 = *(const float4*)(T2 + 256 + lane * 4);
    float s0 = sv.x * w0.x + sv.y * w0.y + sv.z * w0.z + sv.w * w0.w;
    float s1 = sv.x * w1.x + sv.y * w1.y + sv.z * w1.z + sv.w * w1.w;
    s0 = wred_sum(s0);
    s1 = wred_sum(s1);
    if (lane == 0) {
        phi[n0 + w] = tanhf(s0 + t2b[0]) * 3.14159265358979323846f;
        psi[n0 + w] = tanhf(s1 + t2b[1]) * 3.14159265358979323846f;
    }
}

// ---------------- CSOCRG kernel smoothing ----------------
__global__ __launch_bounds__(256) void k_kern(const float* __restrict__ latent,
                                              const float* __restrict__ alpha,
                                              float* __restrict__ out,
                                              short* __restrict__ outb) {
    __shared__ float wl[512];
    __shared__ float partial[4];
    int i = blockIdx.x, t = threadIdx.x;
    float ai = alpha[i];
    float w0, w1;
    {
        int j = t;
        float dd = fabsf((float)(i - j)) + 1e-4f;
        float ap = 0.5f * (ai + alpha[j]);
        w0 = exp2f(-ap * __log2f(dd) - dd * 0.048089834696298776f); // log2(e)/30
        j = t + 256;
        dd = fabsf((float)(i - j)) + 1e-4f;
        ap = 0.5f * (ai + alpha[j]);
        w1 = exp2f(-ap * __log2f(dd) - dd * 0.048089834696298776f);
    }
    wl[t] = w0; wl[t + 256] = w1;
    float s = wred_sum(w0 + w1);
    if ((t & 63) == 0) partial[t >> 6] = s;
    __syncthreads();
    float S = partial[0] + partial[1] + partial[2] + partial[3];
    float inv = 1.f / (S + 1e-8f);
    float acc = 0.f;
    #pragma unroll 4
    for (int j = 0; j < 512; ++j) acc += wl[j] * latent[(size_t)j * 256 + t];
    float v = acc * inv;
    out[(size_t)i * 256 + t] = v;
    outb[(size_t)i * 256 + t] = f2bf(v);
}

// ---------------- distogram v8: software-prefetch pipeline, 256-thr blocks -----
// grid = (32 jt, 64 it), 256 threads (4 waves). wave w: i = it*8 + w*2 + {0,1}.
// hij[n][512]: cols 0..255 = hi part, 256..511 = hj part.
__global__ __launch_bounds__(256) void k_disto8(const float* __restrict__ hij,
                                                const short* __restrict__ F2bf,
                                                const float* __restrict__ f2b,
                                                float* __restrict__ out) {
    __shared__ __align__(16) short hjs[16][264];   // bf16 hj strip
    int jt = blockIdx.x, it = blockIdx.y;
    int j0 = jt * 16;
    int t = threadIdx.x;
    {   // stage 16 rows x 256 cols bf16: 256 thr x 16 elems
        int r = t >> 4, c = (t & 15) * 16;
        const float* src = hij + (size_t)(j0 + r) * 512 + 256 + c;
        float4 v0 = *(const float4*)(src);
        float4 v1 = *(const float4*)(src + 4);
        float4 v2 = *(const float4*)(src + 8);
        float4 v3 = *(const float4*)(src + 12);
        union { int i[4]; short8 s; } u0, u1;
        u0.i[0] = cvt_pk_bf16(v0.x, v0.y);
        u0.i[1] = cvt_pk_bf16(v0.z, v0.w);
        u0.i[2] = cvt_pk_bf16(v1.x, v1.y);
        u0.i[3] = cvt_pk_bf16(v1.z, v1.w);
        u1.i[0] = cvt_pk_bf16(v2.x, v2.y);
        u1.i[1] = cvt_pk_bf16(v2.z, v2.w);
        u1.i[2] = cvt_pk_bf16(v3.x, v3.y);
        u1.i[3] = cvt_pk_bf16(v3.z, v3.w);
        *(short8*)&hjs[r][c] = u0.s;
        *(short8*)&hjs[r][c + 8] = u1.s;
    }
    __syncthreads();
    int w = t >> 6, lane = t & 63;
    int cr = lane & 15, g = lane >> 4;
    int i0 = it * 8 + w * 2;
    const float* hr0 = hij + (size_t)i0 * 512;
    const float* hr1 = hr0 + 512;
    float bb[4];
    #pragma unroll
    for (int c = 0; c < 4; ++c) bb[c] = f2b[c * 16 + cr];
    f32x4 acc[2][4];
    #pragma unroll
    for (int ii = 0; ii < 2; ++ii)
        #pragma unroll
        for (int c = 0; c < 4; ++c) acc[ii][c] = (f32x4){0.f,0.f,0.f,0.f};
    // pipeline registers (next-iteration operands)
    short8 Bp[4]; short8 jp; float4 hap[2], hbp[2];
    {
        int kb = g * 8;
        #pragma unroll
        for (int c = 0; c < 4; ++c)
            Bp[c] = *(const short8*)(F2bf + (size_t)(c * 16 + cr) * 256 + kb);
        jp = *(const short8*)&hjs[cr][kb];
        hap[0] = *(const float4*)(hr0 + kb); hbp[0] = *(const float4*)(hr0 + kb + 4);
        hap[1] = *(const float4*)(hr1 + kb); hbp[1] = *(const float4*)(hr1 + kb + 4);
    }
    #pragma unroll 1
    for (int ks = 0; ks < 8; ++ks) {
        short8 Bc0 = Bp[0], Bc1 = Bp[1], Bc2 = Bp[2], Bc3 = Bp[3];
        union { short8 s; int i[4]; } jc; jc.s = jp;
        float4 a0 = hap[0], b0 = hbp[0], a1 = hap[1], b1 = hbp[1];
        if (ks < 7) {
            int kn = (ks + 1) * 32 + g * 8;
            #pragma unroll
            for (int c = 0; c < 4; ++c)
                Bp[c] = *(const short8*)(F2bf + (size_t)(c * 16 + cr) * 256 + kn);
            jp = *(const short8*)&hjs[cr][kn];
            hap[0] = *(const float4*)(hr0 + kn); hbp[0] = *(const float4*)(hr0 + kn + 4);
            hap[1] = *(const float4*)(hr1 + kn); hbp[1] = *(const float4*)(hr1 + kn + 4);
        }
        float jf[8];
        #pragma unroll
        for (int q = 0; q < 4; ++q) {
            union { int i; float f; } lo, hi2;
            lo.i = jc.i[q] << 16;
            hi2.i = jc.i[q] & 0xffff0000;
            jf[q * 2] = lo.f;
            jf[q * 2 + 1] = hi2.f;
        }
        #pragma unroll
        for (int ii = 0; ii < 2; ++ii) {
            float4 ha = (ii == 0) ? a0 : a1;
            float4 hb = (ii == 0) ? b0 : b1;
            float p0 = gelu_sig(ha.x + jf[0]);
            float p1 = gelu_sig(ha.y + jf[1]);
            float p2 = gelu_sig(ha.z + jf[2]);
            float p3 = gelu_sig(ha.w + jf[3]);
            float p4 = gelu_sig(hb.x + jf[4]);
            float p5 = gelu_sig(hb.y + jf[5]);
            float p6 = gelu_sig(hb.z + jf[6]);
            float p7 = gelu_sig(hb.w + jf[7]);
            union { int i[4]; short8 s; } u;
            u.i[0] = cvt_pk_bf16(p0, p1);
            u.i[1] = cvt_pk_bf16(p2, p3);
            u.i[2] = cvt_pk_bf16(p4, p5);
            u.i[3] = cvt_pk_bf16(p6, p7);
            acc[ii][0] = __builtin_amdgcn_mfma_f32_16x16x32_bf16(u.s, Bc0, acc[ii][0], 0, 0, 0);
            acc[ii][1] = __builtin_amdgcn_mfma_f32_16x16x32_bf16(u.s, Bc1, acc[ii][1], 0, 0, 0);
            acc[ii][2] = __builtin_amdgcn_mfma_f32_16x16x32_bf16(u.s, Bc2, acc[ii][2], 0, 0, 0);
            acc[ii][3] = __builtin_amdgcn_mfma_f32_16x16x32_bf16(u.s, Bc3, acc[ii][3], 0, 0, 0);
        }
    }
    #pragma unroll
    for (int ii = 0; ii < 2; ++ii) {
        #pragma unroll
        for (int r = 0; r < 4; ++r) {
            int jl = g * 4 + r;
            float* op = out + ((size_t)(i0 + ii) * 512 + j0 + jl) * 64;
            op[cr]      = acc[ii][0][r] + bb[0];
            op[cr + 16] = acc[ii][1][r] + bb[1];
            op[cr + 32] = acc[ii][2][r] + bb[2];
            op[cr + 48] = acc[ii][3][r] + bb[3];
        }
    }
}

// ---------------- diffusion init (closed form) ----------------
__global__ __launch_bounds__(64) void k_diffusion(const float* __restrict__ latent,
                                                  const float* __restrict__ Cp,
                                                  const float* __restrict__ cpb,
                                                  const float* __restrict__ noise,
                                                  float* __restrict__ xc) {
    int n = blockIdx.x, lane = threadIdx.x;
    float4 lv = *(const float4*)(latent + (size_t)n * 256 + lane * 4);
    const float CN = 40320.0f / 16777216.0f;  // 8!/8^8
    float s[3];
    #pragma unroll
    for (int c = 0; c < 3; ++c) {
        float4 w = *(const float4*)(Cp + c * 256 + lane * 4);
        float v = lv.x * w.x + lv.y * w.y + lv.z * w.z + lv.w * w.w;
        s[c] = wred_sum(v);
    }
    if (lane == 0) {
        #pragma unroll
        for (int c = 0; c < 3; ++c) {
            float tg = s[c] + cpb[c];
            xc[n * 3 + c] = CN * noise[n * 3 + c] + (1.f - CN) * tg;
        }
    }
}

extern "C" void kernel_launch(void* const* d_in, const int* in_sizes, int n_in,
                              void* d_out, int out_size, void* d_ws, size_t ws_size,
                              hipStream_t stream) {
    const int*   tokens = (const int*)d_in[0];
    const float* emb  = (const float*)d_in[1];
    const float* Wqkv = (const float*)d_in[2];
    const float* bqkv = (const float*)d_in[3];
    const float* Wo   = (const float*)d_in[4];
    const float* bo   = (const float*)d_in[5];
    const float* g1   = (const float*)d_in[6];
    const float* be1  = (const float*)d_in[7];
    const float* W1   = (const float*)d_in[8];
    const float* b1   = (const float*)d_in[9];
    const float* W2   = (const float*)d_in[10];
    const float* b2   = (const float*)d_in[11];
    const float* g2   = (const float*)d_in[12];
    const float* be2  = (const float*)d_in[13];
    const float* A1   = (const float*)d_in[14];
    const float* a1b  = (const float*)d_in[15];
    const float* A2   = (const float*)d_in[16];
    const float* a2b  = (const float*)d_in[17];
    const float* Cf   = (const float*)d_in[18];
    const float* cb   = (const float*)d_in[19];
    const float* F1   = (const float*)d_in[20];
    const float* f1b  = (const float*)d_in[21];
    const float* F2   = (const float*)d_in[22];
    const float* f2b  = (const float*)d_in[23];
    const float* T1   = (const float*)d_in[24];
    const float* t1b  = (const float*)d_in[25];
    const float* T2   = (const float*)d_in[26];
    const float* t2b  = (const float*)d_in[27];
    const float* Cp   = (const float*)d_in[28];
    const float* cpb  = (const float*)d_in[29];
    const float* noise= (const float*)d_in[30];

    float* ws   = (float*)d_ws;
    float* x    = ws;                 // 131072
    float* y2   = ws + 131072;        // 131072
    float* hij  = ws + 262144;        // 262144 (512x512)
    short* S    = (short*)(ws + 524288);
    short* x_bf    = S;               // 131072 shorts
    short* obuf_bf = S + 131072;      // 131072
    short* h1_bf   = S + 262144;      // 524288
    short* hh_bf   = S + 786432;      // 131072
    short* lat_bf  = S + 917504;      // 131072
    short* F2bf    = S + 1048576;     // 16384
    short* qkv_bf  = S + 1064960;     // 393216
    short* vt      = S + 1458176;     // 131072
    short* Wqkv_bf = S + 1589248;     // 1179648
    short* Wo_bf   = S + 2768896;     // 393216
    short* W1_bf   = S + 3162112;     // 1572864
    short* W2_bf   = S + 4734976;     // 1572864
    short* A1_bf   = S + 6307840;     // 65536
    short* Cf_bf   = S + 6373376;     // 65536
    short* F1_bf   = S + 6438912;     // 131072
    short* T1_bf   = S + 6569984;     // 65536

    float* out = (float*)d_out;
    float* o_latent  = out;                // 131072
    float* o_alpha   = out + 131072;       // 512
    float* o_contact = out + 131584;       // 262144
    float* o_disto   = out + 393728;       // 16777216
    float* o_phi     = out + 17170944;     // 512
    float* o_psi     = out + 17171456;     // 512
    float* o_xc      = out + 17171968;     // 1536

    CvtPack p;
    p.s[0] = Wqkv; p.d[0] = Wqkv_bf; p.n[0] = 1179648;
    p.s[1] = Wo;   p.d[1] = Wo_bf;   p.n[1] = 393216;
    p.s[2] = W1;   p.d[2] = W1_bf;   p.n[2] = 1572864;
    p.s[3] = W2;   p.d[3] = W2_bf;   p.n[3] = 1572864;
    p.s[4] = A1;   p.d[4] = A1_bf;   p.n[4] = 65536;
    p.s[5] = Cf;   p.d[5] = Cf_bf;   p.n[5] = 65536;
    p.s[6] = F1;   p.d[6] = F1_bf;   p.n[6] = 131072;
    p.s[7] = T1;   p.d[7] = T1_bf;   p.n[7] = 65536;
    p.s[8] = F2;   p.d[8] = F2bf;    p.n[8] = 16384;
    k_cvt_embed<<<1024, 256, 0, stream>>>(p, tokens, emb, x, x_bf);

    for (int l = 0; l < 6; ++l) {
        k_gemm16<<<dim3(48, 32), 64, 0, stream>>>(x_bf, Wqkv_bf + (size_t)l * 196608,
            bqkv + l * 768, nullptr, qkv_bf, vt, 768, 256, 256, 0);
        k_attn3<<<dim3(8, 32), 64, 0, stream>>>(qkv_bf, vt, obuf_bf);
        k_gemm16<<<dim3(16, 32), 64, 0, stream>>>(obuf_bf, Wo_bf + (size_t)l * 65536,
            bo + l * 256, y2, nullptr, nullptr, 256, 256, 256, 0);
        k_ln<<<512, 64, 0, stream>>>(x, y2, g1 + l * 256, be1 + l * 256, x, x_bf);
        k_gemm16<<<dim3(64, 32), 64, 0, stream>>>(x_bf, W1_bf + (size_t)l * 262144,
            b1 + l * 1024, nullptr, h1_bf, nullptr, 1024, 256, 256, 1);
        k_gemm16<<<dim3(16, 32), 64, 0, stream>>>(h1_bf, W2_bf + (size_t)l * 262144,
            b2 + l * 256, y2, nullptr, nullptr, 256, 1024, 1024, 0);
        k_ln<<<512, 64, 0, stream>>>(x, y2, g2 + l * 256, be2 + l * 256, x, x_bf);
    }

    // alpha head (fused GEMM + reduce)
    k_alpha2<<<32, 1024, 0, stream>>>(x_bf, A1_bf, a1b, A2, a2b, o_alpha);
    // CSOCRG smoothing -> latent output (fp32 + bf16)
    k_kern<<<512, 256, 0, stream>>>(x, o_alpha, o_latent, lat_bf);
    // contact head
    k_gemm16<<<dim3(16, 32), 64, 0, stream>>>(lat_bf, Cf_bf, cb, nullptr, hh_bf, nullptr,
                                              256, 256, 256, 0);
    k_gemm16<<<dim3(32, 32), 64, 0, stream>>>(hh_bf, hh_bf, nullptr, o_contact, nullptr,
                                              nullptr, 512, 256, 256, 3);
    // distogram head: merged F1 GEMM then pipelined disto
    k_gemm_f1<<<dim3(32, 32), 64, 0, stream>>>(lat_bf, F1_bf, f1b, hij);
    k_disto8<<<dim3(32, 64), 256, 0, stream>>>(hij, F2bf, f2b, o_disto);
    // torsion head (fused)
    k_tors2<<<32, 1024, 0, stream>>>(lat_bf, T1_bf, t1b, T2, t2b, o_phi, o_psi);
    // diffusion init
    k_diffusion<<<512, 64, 0, stream>>>(o_latent, Cp, cpb, noise, o_xc);
}

// Round 14
// 339.716 us; speedup vs baseline: 1.0395x; 1.0395x over previous
//
#include <hip/hip_runtime.h>
#include <hip/hip_bf16.h>

#define DEV __device__ __forceinline__

typedef float f32x4 __attribute__((ext_vector_type(4)));
typedef short short8 __attribute__((ext_vector_type(8)));
typedef short short4v __attribute__((ext_vector_type(4)));

#if __has_builtin(__builtin_amdgcn_exp2f)
#define EXP2F __builtin_amdgcn_exp2f
#else
#define EXP2F exp2f
#endif
#if __has_builtin(__builtin_amdgcn_rcpf)
#define RCPF __builtin_amdgcn_rcpf
#else
#define RCPF(x) (1.f / (x))
#endif

DEV short f2bf(float f) {
    union { float f; unsigned u; } c; c.f = f;
    unsigned r = (c.u + 0x7FFFu + ((c.u >> 16) & 1u)) >> 16;  // RNE
    return (short)r;
}

DEV int cvt_pk_bf16(float lo, float hi) {
    int d;
    asm("v_cvt_pk_bf16_f32 %0, %1, %2" : "=v"(d) : "v"(lo), "v"(hi));
    return d;
}

// lean tanh-approx gelu: HW exp2/rcp only. max |err| vs erf-gelu ~2e-4.
DEV float gelu_fast(float x) {
    float x2 = x * x;
    float y = x * __builtin_fmaf(0.0356774081f, x2, 0.7978845608f);
    y = fminf(fmaxf(y, -15.f), 15.f);
    float e = EXP2F(y * 2.8853900817779268f);     // e^(2y)
    float r = RCPF(e + 1.f);
    float t = (e - 1.f) * r;                      // tanh(y)
    return 0.5f * x * (1.f + t);
}

// sigmoid-form gelu: x*sigmoid(1.702x), 5 VALU. disto A-operand only.
DEV float gelu_sig(float x) {
    float e = EXP2F(x * -2.4555282f);   // exp(-1.702x)
    return x * RCPF(1.f + e);
}

DEV float wred_sum(float v) {
    #pragma unroll
    for (int off = 1; off < 64; off <<= 1) v += __shfl_xor(v, off);
    return v;
}

// ---------------- fused weight-cvt (blocks 512..1023) + embed (0..511) --------
struct CvtPack {
    const float* s[9];
    short* d[9];
    int n[9];
};
__global__ __launch_bounds__(256) void k_cvt_embed(CvtPack p,
                                                   const int* __restrict__ tokens,
                                                   const float* __restrict__ emb,
                                                   float* __restrict__ x,
                                                   short* __restrict__ xb) {
    if (blockIdx.x < 512) {
        int n = blockIdx.x, d = threadIdx.x;
        int tok = tokens[n];
        float div = expf((float)((d >> 1) * 2) * -0.035977892079030837f); // -ln(1e4)/256
        float arg = (float)n * div;
        float pe = (d & 1) ? cosf(arg) : sinf(arg);
        float v = emb[tok * 256 + d] + pe;
        x[n * 256 + d] = v;
        xb[n * 256 + d] = f2bf(v);
        return;
    }
    int bid = blockIdx.x - 512;
    #pragma unroll 1
    for (int seg = 0; seg < 9; ++seg) {
        int n4 = p.n[seg] >> 2;
        const float4* src = (const float4*)p.s[seg];
        short4v* dst = (short4v*)p.d[seg];
        for (int i = bid * 256 + threadIdx.x; i < n4; i += 512 * 256) {
            float4 v = src[i];
            short4v o;
            o[0] = f2bf(v.x); o[1] = f2bf(v.y); o[2] = f2bf(v.z); o[3] = f2bf(v.w);
            dst[i] = o;
        }
    }
}

// ---------------- bf16 MFMA GEMM, 16x16 tile per wave (r11-verified) ----------
__global__ __launch_bounds__(64) void k_gemm16(const short* __restrict__ A,
                                               const short* __restrict__ W,
                                               const float* __restrict__ bias,
                                               float* __restrict__ outf,
                                               short* __restrict__ outb,
                                               short* __restrict__ vt,
                                               int M, int K, int ldw, int act) {
    int m0 = blockIdx.x * 16, n0 = blockIdx.y * 16;
    int lane = threadIdx.x;
    int cr = lane & 15, g = lane >> 4;
    const short* a0 = A + (size_t)(n0 + cr) * K + g * 8;
    const short* b0 = W + (size_t)(m0 + cr) * ldw + g * 8;
    f32x4 acc = {0.f, 0.f, 0.f, 0.f};
    #pragma unroll 1
    for (int kc = 0; kc < K; kc += 256) {
        short8 af[8], bf8[8];
        #pragma unroll
        for (int ki = 0; ki < 8; ++ki) af[ki] = *(const short8*)(a0 + kc + ki * 32);
        #pragma unroll
        for (int ki = 0; ki < 8; ++ki) bf8[ki] = *(const short8*)(b0 + kc + ki * 32);
        #pragma unroll
        for (int ki = 0; ki < 8; ++ki)
            acc = __builtin_amdgcn_mfma_f32_16x16x32_bf16(af[ki], bf8[ki], acc, 0, 0, 0);
    }
    float bb = bias ? bias[m0 + cr] : 0.f;
    int m = m0 + cr;
    #pragma unroll
    for (int r = 0; r < 4; ++r) {
        int row = n0 + g * 4 + r;
        float v = acc[r] + bb;
        if (act == 1) v = fmaxf(v, 0.f);
        else if (act == 2) v = gelu_fast(v);
        else if (act == 3) v = 1.f / (1.f + __expf(-v));
        if (outf) outf[(size_t)row * M + m] = v;
        if (outb) outb[(size_t)row * M + m] = f2bf(v);
        if (vt && m >= 512) vt[(size_t)(m - 512) * 512 + row] = f2bf(v);
    }
}

// ---------------- MFMA flash attention v3 (verified r8) ----------------
__global__ __launch_bounds__(64) void k_attn3(const short* __restrict__ qkvb,
                                              const short* __restrict__ vt,
                                              short* __restrict__ obuf_bf) {
    __shared__ __align__(16) short Pb[16][40];
    int h = blockIdx.x, qt = blockIdx.y;
    int lane = threadIdx.x;
    int cr = lane & 15, g = lane >> 4;
    int qb = qt * 16;
    short8 qf = *(const short8*)(qkvb + (size_t)(qb + cr) * 768 + h * 32 + g * 8);
    f32x4 s[32];
    #pragma unroll
    for (int jt = 0; jt < 32; ++jt) {
        short8 kf = *(const short8*)(qkvb + (size_t)(jt * 16 + cr) * 768 + 256 + h * 32 + g * 8);
        f32x4 z = {0.f, 0.f, 0.f, 0.f};
        s[jt] = __builtin_amdgcn_mfma_f32_16x16x32_bf16(qf, kf, z, 0, 0, 0);
    }
    const float sc = 0.17677669529663687f; // 1/sqrt(32)
    float m[4], l[4];
    #pragma unroll
    for (int r = 0; r < 4; ++r) {
        float mm = -1e30f;
        #pragma unroll
        for (int jt = 0; jt < 32; ++jt) mm = fmaxf(mm, s[jt][r]);
        #pragma unroll
        for (int off = 1; off < 16; off <<= 1) mm = fmaxf(mm, __shfl_xor(mm, off));
        m[r] = mm * sc;
    }
    #pragma unroll
    for (int r = 0; r < 4; ++r) {
        float ll = 0.f;
        #pragma unroll
        for (int jt = 0; jt < 32; ++jt) {
            float p = __expf(s[jt][r] * sc - m[r]);
            s[jt][r] = p;
            ll += p;
        }
        #pragma unroll
        for (int off = 1; off < 16; off <<= 1) ll += __shfl_xor(ll, off);
        l[r] = ll;
    }
    const short* vth0 = vt + (size_t)(h * 32 + cr) * 512;
    const short* vth1 = vt + (size_t)(h * 32 + 16 + cr) * 512;
    f32x4 o0 = {0.f,0.f,0.f,0.f}, o1 = o0;
    #pragma unroll
    for (int c = 0; c < 16; ++c) {
        #pragma unroll
        for (int r = 0; r < 4; ++r) {
            Pb[4 * g + r][cr]      = f2bf(s[2 * c][r]);
            Pb[4 * g + r][16 + cr] = f2bf(s[2 * c + 1][r]);
        }
        short8 pa = *(const short8*)&Pb[cr][g * 8];
        short8 v0 = *(const short8*)(vth0 + c * 32 + g * 8);
        short8 v1 = *(const short8*)(vth1 + c * 32 + g * 8);
        o0 = __builtin_amdgcn_mfma_f32_16x16x32_bf16(pa, v0, o0, 0, 0, 0);
        o1 = __builtin_amdgcn_mfma_f32_16x16x32_bf16(pa, v1, o1, 0, 0, 0);
    }
    #pragma unroll
    for (int r = 0; r < 4; ++r) {
        float inv = 1.f / l[r];
        int q = qb + 4 * g + r;
        short* op = obuf_bf + (size_t)q * 256 + h * 32;
        op[cr]      = f2bf(o0[r] * inv);
        op[16 + cr] = f2bf(o1[r] * inv);
    }
}

// ---------------- residual + LayerNorm (fp32 + bf16 out) ----------------
__global__ __launch_bounds__(64) void k_ln(const float* xr, const float* y,
                                           const float* __restrict__ g,
                                           const float* __restrict__ b,
                                           float* out, short* outb) {
    int n = blockIdx.x, lane = threadIdx.x;
    float4 xv = *(const float4*)(xr + (size_t)n * 256 + lane * 4);
    float4 yv = *(const float4*)(y + (size_t)n * 256 + lane * 4);
    float t0 = xv.x + yv.x, t1 = xv.y + yv.y, t2 = xv.z + yv.z, t3 = xv.w + yv.w;
    float s = t0 + t1 + t2 + t3;
    float sq = t0 * t0 + t1 * t1 + t2 * t2 + t3 * t3;
    s = wred_sum(s);
    sq = wred_sum(sq);
    float mean = s * (1.f / 256.f);
    float var = sq * (1.f / 256.f) - mean * mean;
    float rstd = rsqrtf(var + 1e-5f);
    float4 gv = *(const float4*)(g + lane * 4);
    float4 bv = *(const float4*)(b + lane * 4);
    float r0 = (t0 - mean) * rstd * gv.x + bv.x;
    float r1 = (t1 - mean) * rstd * gv.y + bv.y;
    float r2 = (t2 - mean) * rstd * gv.z + bv.z;
    float r3 = (t3 - mean) * rstd * gv.w + bv.w;
    *(float4*)(out + (size_t)n * 256 + lane * 4) = make_float4(r0, r1, r2, r3);
    short4v ob; ob[0] = f2bf(r0); ob[1] = f2bf(r1); ob[2] = f2bf(r2); ob[3] = f2bf(r3);
    *(short4v*)(outb + (size_t)n * 256 + lane * 4) = ob;
}

// ---------------- alpha head ----------------
__global__ __launch_bounds__(64) void k_alpha(const float* __restrict__ g,
                                              const float* __restrict__ A2,
                                              const float* __restrict__ a2b,
                                              float* __restrict__ alpha) {
    int n = blockIdx.x, lane = threadIdx.x;
    float4 gv = *(const float4*)(g + (size_t)n * 256 + lane * 4);
    float4 av = *(const float4*)(A2 + lane * 4);
    float s = gv.x * av.x + gv.y * av.y + gv.z * av.z + gv.w * av.w;
    s = wred_sum(s);
    if (lane == 0) {
        float ah = s + a2b[0];
        alpha[n] = 1.2f + 2.3f / (1.f + __expf(-ah));
    }
}

// ---------------- CSOCRG kernel smoothing ----------------
__global__ __launch_bounds__(256) void k_kern(const float* __restrict__ latent,
                                              const float* __restrict__ alpha,
                                              float* __restrict__ out,
                                              short* __restrict__ outb) {
    __shared__ float wl[512];
    __shared__ float partial[4];
    int i = blockIdx.x, t = threadIdx.x;
    float ai = alpha[i];
    float w0, w1;
    {
        int j = t;
        float dd = fabsf((float)(i - j)) + 1e-4f;
        float ap = 0.5f * (ai + alpha[j]);
        w0 = exp2f(-ap * __log2f(dd) - dd * 0.048089834696298776f); // log2(e)/30
        j = t + 256;
        dd = fabsf((float)(i - j)) + 1e-4f;
        ap = 0.5f * (ai + alpha[j]);
        w1 = exp2f(-ap * __log2f(dd) - dd * 0.048089834696298776f);
    }
    wl[t] = w0; wl[t + 256] = w1;
    float s = wred_sum(w0 + w1);
    if ((t & 63) == 0) partial[t >> 6] = s;
    __syncthreads();
    float S = partial[0] + partial[1] + partial[2] + partial[3];
    float inv = 1.f / (S + 1e-8f);
    float acc = 0.f;
    #pragma unroll 4
    for (int j = 0; j < 512; ++j) acc += wl[j] * latent[(size_t)j * 256 + t];
    float v = acc * inv;
    out[(size_t)i * 256 + t] = v;
    outb[(size_t)i * 256 + t] = f2bf(v);
}

// ---------------- distogram v9: 4 i's per wave, 512-block grid ----------------
// grid = (32 jt, 16 it), 512 threads (8 waves). wave w: i = it*32 + w*4 + {0..3}.
__global__ __launch_bounds__(512) void k_disto9(const float* __restrict__ hi,
                                                const float* __restrict__ hj,
                                                const short* __restrict__ F2bf,
                                                const float* __restrict__ f2b,
                                                float* __restrict__ out) {
    __shared__ __align__(16) short hjs[16][264];   // bf16, stride 264 -> 2-way banks
    int jt = blockIdx.x, it = blockIdx.y;
    int j0 = jt * 16;
    int t = threadIdx.x;
    {   // stage 16 rows x 256 cols as bf16: 512 thr x 8 elems
        int r = t >> 5, c = (t & 31) * 8;
        const float* src = hj + (size_t)(j0 + r) * 256 + c;
        float4 v0 = *(const float4*)(src);
        float4 v1 = *(const float4*)(src + 4);
        union { int i[4]; short8 s; } u;
        u.i[0] = cvt_pk_bf16(v0.x, v0.y);
        u.i[1] = cvt_pk_bf16(v0.z, v0.w);
        u.i[2] = cvt_pk_bf16(v1.x, v1.y);
        u.i[3] = cvt_pk_bf16(v1.z, v1.w);
        *(short8*)&hjs[r][c] = u.s;
    }
    __syncthreads();
    int w = t >> 6, lane = t & 63;
    int cr = lane & 15, g = lane >> 4;
    int i0 = it * 32 + w * 4;
    float bb[4];
    #pragma unroll
    for (int c = 0; c < 4; ++c) bb[c] = f2b[c * 16 + cr];
    f32x4 acc[4][4];
    #pragma unroll
    for (int ii = 0; ii < 4; ++ii)
        #pragma unroll
        for (int c = 0; c < 4; ++c) acc[ii][c] = (f32x4){0.f,0.f,0.f,0.f};
    #pragma unroll 1
    for (int ks = 0; ks < 8; ++ks) {
        int kb = ks * 32 + g * 8;
        short8 B[4];
        #pragma unroll
        for (int c = 0; c < 4; ++c)
            B[c] = *(const short8*)(F2bf + (size_t)(c * 16 + cr) * 256 + kb);
        union { short8 s; int i[4]; } jv;
        jv.s = *(const short8*)&hjs[cr][kb];
        float jf[8];
        #pragma unroll
        for (int q = 0; q < 4; ++q) {
            union { int i; float f; } lo, hi2;
            lo.i = jv.i[q] << 16;
            hi2.i = jv.i[q] & 0xffff0000;
            jf[q * 2] = lo.f;
            jf[q * 2 + 1] = hi2.f;
        }
        #pragma unroll
        for (int ii = 0; ii < 4; ++ii) {
            const float* hr = hi + (size_t)(i0 + ii) * 256 + kb;
            float4 ha = *(const float4*)(hr);
            float4 hb = *(const float4*)(hr + 4);
            float p0 = gelu_sig(ha.x + jf[0]);
            float p1 = gelu_sig(ha.y + jf[1]);
            float p2 = gelu_sig(ha.z + jf[2]);
            float p3 = gelu_sig(ha.w + jf[3]);
            float p4 = gelu_sig(hb.x + jf[4]);
            float p5 = gelu_sig(hb.y + jf[5]);
            float p6 = gelu_sig(hb.z + jf[6]);
            float p7 = gelu_sig(hb.w + jf[7]);
            union { int i[4]; short8 s; } u;
            u.i[0] = cvt_pk_bf16(p0, p1);
            u.i[1] = cvt_pk_bf16(p2, p3);
            u.i[2] = cvt_pk_bf16(p4, p5);
            u.i[3] = cvt_pk_bf16(p6, p7);
            #pragma unroll
            for (int c = 0; c < 4; ++c)
                acc[ii][c] = __builtin_amdgcn_mfma_f32_16x16x32_bf16(u.s, B[c], acc[ii][c], 0, 0, 0);
        }
    }
    #pragma unroll
    for (int ii = 0; ii < 4; ++ii) {
        #pragma unroll
        for (int r = 0; r < 4; ++r) {
            int jl = g * 4 + r;
            float* op = out + ((size_t)(i0 + ii) * 512 + j0 + jl) * 64;
            op[cr]      = acc[ii][0][r] + bb[0];
            op[cr + 16] = acc[ii][1][r] + bb[1];
            op[cr + 32] = acc[ii][2][r] + bb[2];
            op[cr + 48] = acc[ii][3][r] + bb[3];
        }
    }
}

// ---------------- torsion head ----------------
__global__ __launch_bounds__(64) void k_torsion(const float* __restrict__ g,
                                                const float* __restrict__ T2,
                                                const float* __restrict__ t2b,
                                                float* __restrict__ phi,
                                                float* __restrict__ psi) {
    int n = blockIdx.x, lane = threadIdx.x;
    float4 gv = *(const float4*)(g + (size_t)n * 256 + lane * 4);
    float4 w0 = *(const float4*)(T2 + lane * 4);
    float4 w1 = *(const float4*)(T2 + 256 + lane * 4);
    float s0 = gv.x * w0.x + gv.y * w0.y + gv.z * w0.z + gv.w * w0.w;
    float s1 = gv.x * w1.x + gv.y * w1.y + gv.z * w1.z + gv.w * w1.w;
    s0 = wred_sum(s0);
    s1 = wred_sum(s1);
    if (lane == 0) {
        phi[n] = tanhf(s0 + t2b[0]) * 3.14159265358979323846f;
        psi[n] = tanhf(s1 + t2b[1]) * 3.14159265358979323846f;
    }
}

// ---------------- diffusion init (closed form) ----------------
__global__ __launch_bounds__(64) void k_diffusion(const float* __restrict__ latent,
                                                  const float* __restrict__ Cp,
                                                  const float* __restrict__ cpb,
                                                  const float* __restrict__ noise,
                                                  float* __restrict__ xc) {
    int n = blockIdx.x, lane = threadIdx.x;
    float4 lv = *(const float4*)(latent + (size_t)n * 256 + lane * 4);
    const float CN = 40320.0f / 16777216.0f;  // 8!/8^8
    float s[3];
    #pragma unroll
    for (int c = 0; c < 3; ++c) {
        float4 w = *(const float4*)(Cp + c * 256 + lane * 4);
        float v = lv.x * w.x + lv.y * w.y + lv.z * w.z + lv.w * w.w;
        s[c] = wred_sum(v);
    }
    if (lane == 0) {
        #pragma unroll
        for (int c = 0; c < 3; ++c) {
            float tg = s[c] + cpb[c];
            xc[n * 3 + c] = CN * noise[n * 3 + c] + (1.f - CN) * tg;
        }
    }
}

extern "C" void kernel_launch(void* const* d_in, const int* in_sizes, int n_in,
                              void* d_out, int out_size, void* d_ws, size_t ws_size,
                              hipStream_t stream) {
    const int*   tokens = (const int*)d_in[0];
    const float* emb  = (const float*)d_in[1];
    const float* Wqkv = (const float*)d_in[2];
    const float* bqkv = (const float*)d_in[3];
    const float* Wo   = (const float*)d_in[4];
    const float* bo   = (const float*)d_in[5];
    const float* g1   = (const float*)d_in[6];
    const float* be1  = (const float*)d_in[7];
    const float* W1   = (const float*)d_in[8];
    const float* b1   = (const float*)d_in[9];
    const float* W2   = (const float*)d_in[10];
    const float* b2   = (const float*)d_in[11];
    const float* g2   = (const float*)d_in[12];
    const float* be2  = (const float*)d_in[13];
    const float* A1   = (const float*)d_in[14];
    const float* a1b  = (const float*)d_in[15];
    const float* A2   = (const float*)d_in[16];
    const float* a2b  = (const float*)d_in[17];
    const float* Cf   = (const float*)d_in[18];
    const float* cb   = (const float*)d_in[19];
    const float* F1   = (const float*)d_in[20];
    const float* f1b  = (const float*)d_in[21];
    const float* F2   = (const float*)d_in[22];
    const float* f2b  = (const float*)d_in[23];
    const float* T1   = (const float*)d_in[24];
    const float* t1b  = (const float*)d_in[25];
    const float* T2   = (const float*)d_in[26];
    const float* t2b  = (const float*)d_in[27];
    const float* Cp   = (const float*)d_in[28];
    const float* cpb  = (const float*)d_in[29];
    const float* noise= (const float*)d_in[30];

    float* ws   = (float*)d_ws;
    float* x    = ws;                 // 131072
    float* y2   = ws + 131072;        // 131072
    float* gbuf = ws + 262144;        // 131072
    float* hi   = ws + 393216;        // 131072
    float* hj   = ws + 524288;        // 131072
    short* S    = (short*)(ws + 655360);
    short* x_bf    = S;               // 131072 shorts
    short* obuf_bf = S + 131072;      // 131072
    short* h1_bf   = S + 262144;      // 524288
    short* hh_bf   = S + 786432;      // 131072
    short* lat_bf  = S + 917504;      // 131072
    short* F2bf    = S + 1048576;     // 16384
    short* qkv_bf  = S + 1064960;     // 393216
    short* vt      = S + 1458176;     // 131072
    short* Wqkv_bf = S + 1589248;     // 1179648
    short* Wo_bf   = S + 2768896;     // 393216
    short* W1_bf   = S + 3162112;     // 1572864
    short* W2_bf   = S + 4734976;     // 1572864
    short* A1_bf   = S + 6307840;     // 65536
    short* Cf_bf   = S + 6373376;     // 65536
    short* F1_bf   = S + 6438912;     // 131072
    short* T1_bf   = S + 6569984;     // 65536

    float* out = (float*)d_out;
    float* o_latent  = out;                // 131072
    float* o_alpha   = out + 131072;       // 512
    float* o_contact = out + 131584;       // 262144
    float* o_disto   = out + 393728;       // 16777216
    float* o_phi     = out + 17170944;     // 512
    float* o_psi     = out + 17171456;     // 512
    float* o_xc      = out + 17171968;     // 1536

    CvtPack p;
    p.s[0] = Wqkv; p.d[0] = Wqkv_bf; p.n[0] = 1179648;
    p.s[1] = Wo;   p.d[1] = Wo_bf;   p.n[1] = 393216;
    p.s[2] = W1;   p.d[2] = W1_bf;   p.n[2] = 1572864;
    p.s[3] = W2;   p.d[3] = W2_bf;   p.n[3] = 1572864;
    p.s[4] = A1;   p.d[4] = A1_bf;   p.n[4] = 65536;
    p.s[5] = Cf;   p.d[5] = Cf_bf;   p.n[5] = 65536;
    p.s[6] = F1;   p.d[6] = F1_bf;   p.n[6] = 131072;
    p.s[7] = T1;   p.d[7] = T1_bf;   p.n[7] = 65536;
    p.s[8] = F2;   p.d[8] = F2bf;    p.n[8] = 16384;
    k_cvt_embed<<<1024, 256, 0, stream>>>(p, tokens, emb, x, x_bf);

    for (int l = 0; l < 6; ++l) {
        k_gemm16<<<dim3(48, 32), 64, 0, stream>>>(x_bf, Wqkv_bf + (size_t)l * 196608,
            bqkv + l * 768, nullptr, qkv_bf, vt, 768, 256, 256, 0);
        k_attn3<<<dim3(8, 32), 64, 0, stream>>>(qkv_bf, vt, obuf_bf);
        k_gemm16<<<dim3(16, 32), 64, 0, stream>>>(obuf_bf, Wo_bf + (size_t)l * 65536,
            bo + l * 256, y2, nullptr, nullptr, 256, 256, 256, 0);
        k_ln<<<512, 64, 0, stream>>>(x, y2, g1 + l * 256, be1 + l * 256, x, x_bf);
        k_gemm16<<<dim3(64, 32), 64, 0, stream>>>(x_bf, W1_bf + (size_t)l * 262144,
            b1 + l * 1024, nullptr, h1_bf, nullptr, 1024, 256, 256, 1);
        k_gemm16<<<dim3(16, 32), 64, 0, stream>>>(h1_bf, W2_bf + (size_t)l * 262144,
            b2 + l * 256, y2, nullptr, nullptr, 256, 1024, 1024, 0);
        k_ln<<<512, 64, 0, stream>>>(x, y2, g2 + l * 256, be2 + l * 256, x, x_bf);
    }

    // alpha head (pre-smoothing latent)
    k_gemm16<<<dim3(16, 32), 64, 0, stream>>>(x_bf, A1_bf, a1b, gbuf, nullptr, nullptr,
                                              256, 256, 256, 2);
    k_alpha<<<512, 64, 0, stream>>>(gbuf, A2, a2b, o_alpha);
    // CSOCRG smoothing -> latent output (fp32 + bf16)
    k_kern<<<512, 256, 0, stream>>>(x, o_alpha, o_latent, lat_bf);
    // contact head
    k_gemm16<<<dim3(16, 32), 64, 0, stream>>>(lat_bf, Cf_bf, cb, nullptr, hh_bf, nullptr,
                                              256, 256, 256, 0);
    k_gemm16<<<dim3(32, 32), 64, 0, stream>>>(hh_bf, hh_bf, nullptr, o_contact, nullptr,
                                              nullptr, 512, 256, 256, 3);
    // distogram head
    k_gemm16<<<dim3(16, 32), 64, 0, stream>>>(lat_bf, F1_bf, f1b, hi, nullptr, nullptr,
                                              256, 256, 512, 0);
    k_gemm16<<<dim3(16, 32), 64, 0, stream>>>(lat_bf, F1_bf + 256, nullptr, hj, nullptr,
                                              nullptr, 256, 256, 512, 0);
    k_disto9<<<dim3(32, 16), 512, 0, stream>>>(hi, hj, F2bf, f2b, o_disto);
    // torsion head
    k_gemm16<<<dim3(16, 32), 64, 0, stream>>>(lat_bf, T1_bf, t1b, gbuf, nullptr, nullptr,
                                              256, 256, 256, 2);
    k_torsion<<<512, 64, 0, stream>>>(gbuf, T2, t2b, o_phi, o_psi);
    // diffusion init
    k_diffusion<<<512, 64, 0, stream>>>(o_latent, Cp, cpb, noise, o_xc);
}